// Round 5
// baseline (3449.981 us; speedup 1.0000x reference)
//
#include <hip/hip_runtime.h>
#include <hip/hip_bf16.h>
#include <math.h>

typedef __bf16 bf16x8 __attribute__((ext_vector_type(8)));
typedef float  f32x4  __attribute__((ext_vector_type(4)));

// Problem dims: B=8, U=32, L=64, H=512, V=32000, NSPK=16, R=4, E=128, S=2048
// N = B*U = 256 sequences, 4H = 2048 gate cols. All float I/O is fp32.

// Output element offsets (fp32 elements), flat order:
// enc_h, enc_c, memory_bank(S,B,H), lengths, mbu(S,B,H), lengths, hier(B,S)
#define OFF_ENCH 0
#define OFF_ENCC 4096
#define OFF_MB   8192
#define OFF_LEN1 8396800
#define OFF_MBU  8396808
#define OFF_LEN2 16785416
#define OFF_HIER 16785424

// Workspace byte offsets
#define WS_X      0          // X bf16 [16384][512] = 16777216
#define WS_WIH    16777216   // WihT bf16 [2048][512] = 2097152
#define WS_WHH    18874368   // WhhT bf16 [2048][512] = 2097152
#define WS_HBUF   20971520   // 2 x 256*512 bf16 = 524288
#define WS_BAR    21495808   // 4096 (grid barrier: cnt @0, epoch @256B)
#define WS_AGG    21499904   // 8*33*512 fp32 = 540672  -> zero range ends 22040576
#define WS_NODES  22040576   // fp32 540672
#define WS_NODESB 22581248   // bf16 270336
#define WS_NEWN   22851584   // fp32 540672
#define WS_WRELT  23392256   // WrelT bf16 [4][512][512] = 2097152 -> ends 25489408
#define ZERO_WORDS 267264    // (HBUF + BAR + AGG) / 4

__device__ __forceinline__ float sigm(float x) { return 1.0f / (1.0f + expf(-x)); }

__device__ __forceinline__ void async_cp16(const __bf16* g, __bf16* l) {
    __builtin_amdgcn_global_load_lds((const __attribute__((address_space(1))) void*)g,
                                     (__attribute__((address_space(3))) void*)l,
                                     16, 0, 0);
}

// ---------------- init: zero state + constant outputs ----------------
__global__ __launch_bounds__(256) void k_init(unsigned int* zero_base,
                                              const int* lengths, float* out)
{
    int idx = blockIdx.x * 256 + threadIdx.x;
    if (idx < ZERO_WORDS) { zero_base[idx] = 0u; return; }
    int j = idx - ZERO_WORDS;
    if (j < 16384) { out[OFF_HIER + j] = 64.0f; return; }  // hier_matrix = L
    int j2 = j - 16384;
    if (j2 < 16) {
        float v = (float)lengths[j2 & 7];
        out[(j2 < 8 ? OFF_LEN1 : OFF_LEN2) + (j2 & 7)] = v;
    }
}

// ------- convert fp32 -> bf16 transposed: W_ih, W_hh [512][2048]->[2048][512];
// ------- W_rel [4][512][512] -> WrelT [4][j][k] -------
__global__ __launch_bounds__(256) void k_cvtw(const float* __restrict__ Wih,
                                              const float* __restrict__ Whh,
                                              const float* __restrict__ Wrel,
                                              __bf16* __restrict__ WihT,
                                              __bf16* __restrict__ WhhT,
                                              __bf16* __restrict__ WrelT)
{
    __shared__ float tile[64][65];
    int gid = blockIdx.x;                         // 768 blocks
    int tid = threadIdx.x;
    if (gid < 512) {
        const float* Wsrc = (gid >> 8) ? Whh : Wih;
        __bf16*      Wdst = (gid >> 8) ? WhhT : WihT;
        int rem = gid & 255;
        int k0 = (rem >> 5) << 6;
        int c0 = (rem & 31) << 6;
#pragma unroll
        for (int i = 0; i < 16; ++i) {
            int idx = tid + i * 256;
            int kl = idx >> 6, cl = idx & 63;
            tile[cl][kl] = Wsrc[(size_t)(k0 + kl) * 2048 + c0 + cl];
        }
        __syncthreads();
#pragma unroll
        for (int i = 0; i < 16; ++i) {
            int idx = tid + i * 256;
            int cl = idx >> 6, kl = idx & 63;
            Wdst[(size_t)(c0 + cl) * 512 + k0 + kl] = (__bf16)tile[cl][kl];
        }
    } else {
        int rem = gid - 512;                      // 256 blocks: 4 rels x 8 k x 8 j
        int r = rem >> 6;
        int t6 = rem & 63;
        int k0 = (t6 >> 3) << 6, j0 = (t6 & 7) << 6;
        const float* src = Wrel + (size_t)r * 262144;
        __bf16*      dst = WrelT + (size_t)r * 262144;
#pragma unroll
        for (int i = 0; i < 16; ++i) {
            int idx = tid + i * 256;
            int kl = idx >> 6, jl = idx & 63;
            tile[jl][kl] = src[(size_t)(k0 + kl) * 512 + j0 + jl];
        }
        __syncthreads();
#pragma unroll
        for (int i = 0; i < 16; ++i) {
            int idx = tid + i * 256;
            int jl = idx >> 6, kl = idx & 63;
            dst[(size_t)(j0 + jl) * 512 + k0 + kl] = (__bf16)tile[jl][kl];
        }
    }
}

// ---------------- embedding: X[t*256+n][k] = emb[word] + spk[spkid] (bf16) ----------------
__global__ __launch_bounds__(256) void k_embed(const int* __restrict__ src,
                                               const int* __restrict__ speaker,
                                               const float* __restrict__ emb,
                                               const float* __restrict__ spk,
                                               __bf16* __restrict__ X)
{
    int tid = blockIdx.x * 256 + threadIdx.x;   // 16384*64 threads
    int p  = tid >> 6;                          // t*256 + n
    int k8 = (tid & 63) << 3;
    int t = p >> 8, n = p & 255;
    int b = n >> 5, u = n & 31;
    int s = u * 64 + t;
    int word = src[s * 8 + b];                  // src (S,B,1)
    int sid  = speaker[b * 2048 + s];           // speaker (B,S)
    f32x4 e0 = *(const f32x4*)&emb[word * 512 + k8];
    f32x4 e1 = *(const f32x4*)&emb[word * 512 + k8 + 4];
    f32x4 s0 = *(const f32x4*)&spk[sid * 512 + k8];
    f32x4 s1 = *(const f32x4*)&spk[sid * 512 + k8 + 4];
    bf16x8 o;
#pragma unroll
    for (int j = 0; j < 4; ++j) {
        o[j]     = (__bf16)(e0[j] + s0[j]);
        o[4 + j] = (__bf16)(e1[j] + s1[j]);
    }
    *(bf16x8*)&X[p * 512 + k8] = o;
}

// ---------------- persistent LSTM: all 64 steps, grid barrier between steps ----------------
// 256 blocks (1/CU). Block bx: j0 = (bx&31)*16 h-cols (x4 gates), n0 = (bx>>5)*32 rows.
// Waves: rh = w&1 row-half, kh = w>>1 K-half; LDS reduce across kh.
// W_hh^T and W_ih^T fragments preloaded to registers (t-invariant). c in registers.
__global__ __launch_bounds__(256, 1) void k_lstm_all(const __bf16* __restrict__ X,
                                                     const __bf16* __restrict__ WihT,
                                                     const __bf16* __restrict__ WhhT,
                                                     const float* __restrict__ bl,
                                                     __bf16* __restrict__ hb0,
                                                     __bf16* __restrict__ hb1,
                                                     float* __restrict__ out,
                                                     int* __restrict__ bar)
{
    __shared__ float red[2][64][17];
    int tid = threadIdx.x;
    int w = tid >> 6, lane = tid & 63;
    int ml = lane & 15, q = lane >> 4;
    int rh = w & 1, kh = w >> 1;
    int bx = blockIdx.x;
    int j0 = (bx & 31) << 4;
    int n0 = (bx >> 5) << 5;
    int jc = j0 + ml;
    int rowA = n0 + rh * 16 + ml;
    int koff = kh * 256 + q * 8;

    // Preload B fragments (t-invariant): 32+32 bf16x8 = 256 VGPRs
    bf16x8 Bh[32], Bi[32];
    {
        const __bf16* bh = WhhT + (size_t)jc * 512 + koff;
        const __bf16* bi = WihT + (size_t)jc * 512 + koff;
#pragma unroll
        for (int ki = 0; ki < 8; ++ki)
#pragma unroll
            for (int g = 0; g < 4; ++g) {
                Bh[ki * 4 + g] = *(const bf16x8*)(bh + ((size_t)g << 18) + ki * 32);
                Bi[ki * 4 + g] = *(const bf16x8*)(bi + ((size_t)g << 18) + ki * 32);
            }
    }
    float bias[4];
#pragma unroll
    for (int g = 0; g < 4; ++g) bias[g] = bl[g * 512 + jc];
    float c[4] = {0.f, 0.f, 0.f, 0.f};

    int* cnt   = bar;
    int* epoch = bar + 64;   // separate cacheline

    for (int t = 0; t < 64; ++t) {
        const __bf16* hrow = (t & 1 ? hb1 : hb0) + (size_t)rowA * 512 + koff;
        const __bf16* xrow = X + (((size_t)(t << 8) + rowA) << 9) + koff;
        bf16x8 av[8], xv[8];
#pragma unroll
        for (int ki = 0; ki < 8; ++ki) {
            av[ki] = *(const bf16x8*)(hrow + ki * 32);
            xv[ki] = *(const bf16x8*)(xrow + ki * 32);
        }
        f32x4 acc[4] = {};
#pragma unroll
        for (int ki = 0; ki < 8; ++ki)
#pragma unroll
            for (int g = 0; g < 4; ++g) {
                acc[g] = __builtin_amdgcn_mfma_f32_16x16x32_bf16(av[ki], Bh[ki * 4 + g], acc[g], 0, 0, 0);
                acc[g] = __builtin_amdgcn_mfma_f32_16x16x32_bf16(xv[ki], Bi[ki * 4 + g], acc[g], 0, 0, 0);
            }
        if (kh == 1) {
#pragma unroll
            for (int g = 0; g < 4; ++g)
#pragma unroll
                for (int r = 0; r < 4; ++r)
                    red[rh][lane][g * 4 + r] = acc[g][r];
        }
        __syncthreads();
        if (kh == 0) {
            __bf16* hw = (t & 1) ? hb0 : hb1;   // h(t+1)
#pragma unroll
            for (int r = 0; r < 4; ++r) {
                int n = n0 + rh * 16 + q * 4 + r;
                float pi = acc[0][r] + red[rh][lane][0 * 4 + r] + bias[0];
                float pf = acc[1][r] + red[rh][lane][1 * 4 + r] + bias[1];
                float pg = acc[2][r] + red[rh][lane][2 * 4 + r] + bias[2];
                float po = acc[3][r] + red[rh][lane][3 * 4 + r] + bias[3];
                float ig = sigm(pi), fg = sigm(pf);
                float gg = tanhf(pg), og = sigm(po);
                float cn = fg * c[r] + ig * gg;
                c[r] = cn;
                float hn = og * tanhf(cn);
                hw[(size_t)n * 512 + jc] = (__bf16)hn;
                int b = n >> 5, u = n & 31;
                int s = u * 64 + t;
                out[OFF_MB + ((size_t)s * 8 + b) * 512 + jc] = hn;
            }
        }
        if (t < 63) {
            __threadfence();               // release h stores device-wide
            __syncthreads();
            if (tid == 0) {
                int prev = __hip_atomic_fetch_add(cnt, 1, __ATOMIC_ACQ_REL, __HIP_MEMORY_SCOPE_AGENT);
                if (prev == 256 * (t + 1) - 1) {
                    __hip_atomic_store(epoch, t + 1, __ATOMIC_RELEASE, __HIP_MEMORY_SCOPE_AGENT);
                } else {
                    while (__hip_atomic_load(epoch, __ATOMIC_ACQUIRE, __HIP_MEMORY_SCOPE_AGENT) < t + 1)
                        __builtin_amdgcn_s_sleep(8);
                }
            }
            __syncthreads();
            __threadfence();               // acquire: invalidate stale cached h
        }
    }
}

// ---------------- nodes: utt_h + global mean node (fp32 + bf16 copies) ----------------
__global__ __launch_bounds__(256) void k_nodes(const __bf16* __restrict__ hT,
                                               float* __restrict__ nodes,
                                               __bf16* __restrict__ nodesB)
{
    int b = blockIdx.x;
    for (int k = threadIdx.x; k < 512; k += 256) {
        float sum = 0.f;
        for (int u = 0; u < 32; ++u) {
            float v = (float)hT[(b * 32 + u) * 512 + k];
            nodes[(b * 33 + u) * 512 + k] = v;
            nodesB[(b * 33 + u) * 512 + k] = (__bf16)v;
            sum += v;
        }
        float gm = sum * (1.0f / 32.0f);
        nodes[(b * 33 + 32) * 512 + k] = gm;
        nodesB[(b * 33 + 32) * 512 + k] = (__bf16)gm;
    }
}

// ---------------- edges as one MFMA GEMM: [1024 edges] x [4 rels * 512] x K=512 ----------------
// grid (16,8): bx -> n0 = bx*128 (within 2048 = rel*512 + j), by -> batch b (128 edges).
// Epilogue: rel-masked atomicAdd into agg[dst].
__global__ __launch_bounds__(256) void k_edges_mm(const __bf16* __restrict__ nodesB,
                                                  const __bf16* __restrict__ WrelT,
                                                  const int* __restrict__ edge_src,
                                                  const int* __restrict__ edge_dst,
                                                  const int* __restrict__ rels,
                                                  float* __restrict__ agg)
{
    __shared__ __bf16 As[128 * 32];
    __shared__ __bf16 Bs[128 * 32];
    int tid = threadIdx.x;
    int w = tid >> 6, lane = tid & 63;
    int ml = lane & 15, q = lane >> 4;
    int by = blockIdx.y;                  // batch
    int n0 = blockIdx.x << 7;
    int rel = n0 >> 9, jbase = n0 & 511;
    int mb = (w & 1) * 64, nb = (w >> 1) * 64;
    int lr = lane >> 2, lc = (lane & 3) << 3;
    // per-thread gathered A row bases (2 rows) + B row bases
    const __bf16* ap[2]; const __bf16* bp[2];
#pragma unroll
    for (int i = 0; i < 2; ++i) {
        int r = w * 32 + i * 16 + lr;
        int es = edge_src[by * 128 + r];
        ap[i] = nodesB + ((size_t)by * 33 + es) * 512 + lc;
        bp[i] = WrelT + (size_t)rel * 262144 + (size_t)(jbase + r) * 512 + lc;
    }
    f32x4 acc[4][4] = {};
    for (int k0 = 0; k0 < 512; k0 += 32) {
#pragma unroll
        for (int i = 0; i < 2; ++i) {
            int r = w * 32 + i * 16;
            async_cp16(ap[i] + k0, &As[r * 32]);
            async_cp16(bp[i] + k0, &Bs[r * 32]);
        }
        __syncthreads();
        bf16x8 af[4], bf_[4];
#pragma unroll
        for (int mi = 0; mi < 4; ++mi)
            af[mi] = *(const bf16x8*)&As[(mb + mi * 16 + ml) * 32 + q * 8];
#pragma unroll
        for (int ni = 0; ni < 4; ++ni)
            bf_[ni] = *(const bf16x8*)&Bs[(nb + ni * 16 + ml) * 32 + q * 8];
#pragma unroll
        for (int mi = 0; mi < 4; ++mi)
#pragma unroll
            for (int ni = 0; ni < 4; ++ni)
                acc[mi][ni] = __builtin_amdgcn_mfma_f32_16x16x32_bf16(af[mi], bf_[ni], acc[mi][ni], 0, 0, 0);
        __syncthreads();
    }
#pragma unroll
    for (int mi = 0; mi < 4; ++mi) {
#pragma unroll
        for (int r = 0; r < 4; ++r) {
            int m = mb + mi * 16 + q * 4 + r;
            int eidx = by * 128 + m;
            int er = rels[eidx];
            if (er != rel) continue;
            int ed = edge_dst[eidx];
            float* dst = &agg[((size_t)by * 33 + ed) * 512 + jbase];
#pragma unroll
            for (int ni = 0; ni < 4; ++ni)
                atomicAdd(dst + nb + ni * 16 + ml, acc[mi][ni][r]);
        }
    }
}

// ---------------- GNN gate fusion: grid (264 nodes, 8 j-tiles), in-block K-split ----------------
__global__ __launch_bounds__(256) void k_gnn(const float* __restrict__ nodes,
                                             const float* __restrict__ agg,
                                             const float* __restrict__ Wself,
                                             const float* __restrict__ bgnn,
                                             const float* __restrict__ Wg1,
                                             const float* __restrict__ Wg2,
                                             float* __restrict__ newn,
                                             float* __restrict__ out)
{
    __shared__ float nd[512], ag[512];
    __shared__ float red[4][3][64];
    int vg = blockIdx.x;                 // 0..263
    int j0 = blockIdx.y << 6;            // 8 tiles of 64 cols
    int b = vg / 33, v = vg % 33;
    int tid = threadIdx.x;
    for (int k = tid; k < 512; k += 256) {
        nd[k] = nodes[vg * 512 + k];
        ag[k] = agg[vg * 512 + k];
    }
    __syncthreads();
    int jl = tid & 63, kq = tid >> 6;
    int jj = j0 + jl;
    int kbase = kq << 7;
    float a_s = 0.f, a1 = 0.f, a2 = 0.f;
#pragma unroll 4
    for (int kk = 0; kk < 128; ++kk) {
        int k = kbase + kk;
        float ndk = nd[k], agk = ag[k];
        a_s += ndk * Wself[k * 512 + jj];
        a1  += ndk * Wg1[k * 512 + jj];
        a2  += agk * Wg2[k * 512 + jj];
    }
    red[kq][0][jl] = a_s;
    red[kq][1][jl] = a1;
    red[kq][2][jl] = a2;
    __syncthreads();
    if (tid < 64) {
        int j = j0 + tid;
        float s0 = red[0][0][tid] + red[1][0][tid] + red[2][0][tid] + red[3][0][tid];
        float s1 = red[0][1][tid] + red[1][1][tid] + red[2][1][tid] + red[3][1][tid];
        float s2 = red[0][2][tid] + red[1][2][tid] + red[2][2][tid] + red[3][2][tid];
        float outv = fmaxf(s0 + ag[j] + bgnn[j], 0.f);
        float gate = sigm(s1 + s2);
        float newv = gate * outv + (1.f - gate) * nd[j];
        newn[vg * 512 + j] = newv;
        if (v == 32) {
            out[OFF_ENCH + b * 512 + j] = newv;
            out[OFF_ENCC + b * 512 + j] = newv;
        }
    }
}

// ---------------- mbu: broadcast utt_upd over L into (S,B,H) ----------------
__global__ __launch_bounds__(256) void k_mbu(const float* __restrict__ newn,
                                             float* __restrict__ out)
{
    int idx = blockIdx.x * 256 + threadIdx.x;
    int k8 = (idx & 63) << 3;
    int rest = idx >> 6;
    int b = rest & 7;
    int s = rest >> 3;
    int u = s >> 6;
    const float* sp = &newn[(b * 33 + u) * 512 + k8];
    f32x4 v0 = *(const f32x4*)sp;
    f32x4 v1 = *(const f32x4*)(sp + 4);
    float* dp = &out[OFF_MBU + (s * 8 + b) * 512 + k8];
    *(f32x4*)dp = v0;
    *(f32x4*)(dp + 4) = v1;
}

extern "C" void kernel_launch(void* const* d_in, const int* in_sizes, int n_in,
                              void* d_out, int out_size, void* d_ws, size_t ws_size,
                              hipStream_t stream)
{
    (void)in_sizes; (void)n_in; (void)out_size; (void)ws_size;
    const int*   src      = (const int*)d_in[0];
    const int*   speaker  = (const int*)d_in[2];
    const int*   lengths  = (const int*)d_in[3];
    const int*   edge_src = (const int*)d_in[4];
    const int*   edge_dst = (const int*)d_in[5];
    const int*   rels     = (const int*)d_in[6];
    const float* emb   = (const float*)d_in[7];
    const float* spk   = (const float*)d_in[8];
    const float* Wih   = (const float*)d_in[9];
    const float* Whh   = (const float*)d_in[10];
    const float* bl    = (const float*)d_in[11];
    const float* Wrel  = (const float*)d_in[12];
    const float* Wself = (const float*)d_in[13];
    const float* bgnn  = (const float*)d_in[14];
    const float* Wg1   = (const float*)d_in[15];
    const float* Wg2   = (const float*)d_in[16];
    float* out = (float*)d_out;
    char*  ws  = (char*)d_ws;

    __bf16* X      = (__bf16*)(ws + WS_X);
    __bf16* WihT   = (__bf16*)(ws + WS_WIH);
    __bf16* WhhT   = (__bf16*)(ws + WS_WHH);
    __bf16* hb0    = (__bf16*)(ws + WS_HBUF);
    __bf16* hb1    = hb0 + 131072;
    int*    bar    = (int*)(ws + WS_BAR);
    float*  agg    = (float*)(ws + WS_AGG);
    float*  nodes  = (float*)(ws + WS_NODES);
    __bf16* nodesB = (__bf16*)(ws + WS_NODESB);
    float*  newn   = (float*)(ws + WS_NEWN);
    __bf16* WrelT  = (__bf16*)(ws + WS_WRELT);

    k_init<<<1109, 256, 0, stream>>>((unsigned int*)(ws + WS_HBUF), lengths, out);
    k_cvtw<<<768, 256, 0, stream>>>(Wih, Whh, Wrel, WihT, WhhT, WrelT);
    k_embed<<<4096, 256, 0, stream>>>(src, speaker, emb, spk, X);
    k_lstm_all<<<256, 256, 0, stream>>>(X, WihT, WhhT, bl, hb0, hb1, out, bar);
    k_nodes<<<8, 256, 0, stream>>>(hb0, nodes, nodesB);
    k_edges_mm<<<dim3(16, 8), 256, 0, stream>>>(nodesB, WrelT, edge_src, edge_dst, rels, agg);
    k_gnn<<<dim3(264, 8), 256, 0, stream>>>(nodes, agg, Wself, bgnn, Wg1, Wg2, newn, out);
    k_mbu<<<4096, 256, 0, stream>>>(newn, out);
}

// Round 6
// 884.691 us; speedup vs baseline: 3.8996x; 3.8996x over previous
//
#include <hip/hip_runtime.h>
#include <hip/hip_bf16.h>
#include <math.h>

typedef __bf16 bf16x8 __attribute__((ext_vector_type(8)));
typedef float  f32x4  __attribute__((ext_vector_type(4)));

// Problem dims: B=8, U=32, L=64, H=512, V=32000, NSPK=16, R=4, E=128, S=2048
// N = B*U = 256 sequences, 4H = 2048 gate cols. All float I/O is fp32.

// Output element offsets (fp32 elements), flat order:
// enc_h, enc_c, memory_bank(S,B,H), lengths, mbu(S,B,H), lengths, hier(B,S)
#define OFF_ENCH 0
#define OFF_ENCC 4096
#define OFF_MB   8192
#define OFF_LEN1 8396800
#define OFF_MBU  8396808
#define OFF_LEN2 16785416
#define OFF_HIER 16785424

// Workspace layout. X region [0,16MB) is dead after the Xg GEMM (split) or after
// the LSTM (fused); WrelT/agg/nodes/newn overlay it (all written post-LSTM).
#define WS_X      0          // X bf16 [16384][512] = 16777216 (alive first phase)
#define WS_WRELT  0          // WrelT bf16 [4][512][512] = 2097152 (post-LSTM overlay)
#define WS_AGG    2097152    // fp32 540672
#define WS_NODES  2637824    // fp32 540672
#define WS_NODESB 3178496    // bf16 270336
#define WS_NEWN   3448832    // fp32 540672 -> ends 3989504 (< 16MB)
#define WS_WIH    16777216   // WihT bf16 [2048][512] = 2097152
#define WS_WHH    18874368   // WhhT bf16 [2048][512] = 2097152
#define WS_HBUF   20971520   // 2 x 256*512 bf16 = 524288
#define WS_BAR    21495808   // 4096 (cnt @ +0, epoch @ +256B) -- zeroed with HBUF
#define WS_XG     21499904   // Xg bf16 [16384][2048] = 67108864 -> ends 88608768
#define WS_SPLIT_NEED 88608768ull
#define ZERO_WORDS 132096    // (HBUF 524288 + BAR 4096) / 4

__device__ __forceinline__ float sigm(float x) { return 1.0f / (1.0f + expf(-x)); }

__device__ __forceinline__ void async_cp16(const __bf16* g, __bf16* l) {
    __builtin_amdgcn_global_load_lds((const __attribute__((address_space(1))) void*)g,
                                     (__attribute__((address_space(3))) void*)l,
                                     16, 0, 0);
}

// ---------------- init: zero h-buffers + barrier, constant outputs ----------------
__global__ __launch_bounds__(256) void k_init(unsigned int* zero_base,
                                              const int* lengths, float* out)
{
    int idx = blockIdx.x * 256 + threadIdx.x;
    if (idx < ZERO_WORDS) { zero_base[idx] = 0u; return; }
    int j = idx - ZERO_WORDS;
    if (j < 16384) { out[OFF_HIER + j] = 64.0f; return; }  // hier_matrix = L
    int j2 = j - 16384;
    if (j2 < 16) {
        float v = (float)lengths[j2 & 7];
        out[(j2 < 8 ? OFF_LEN1 : OFF_LEN2) + (j2 & 7)] = v;
    }
}

// ------- W_ih / W_hh fp32 [512][2048] -> bf16 transposed [2048][512] -------
__global__ __launch_bounds__(256) void k_cvtw(const float* __restrict__ Wih,
                                              const float* __restrict__ Whh,
                                              __bf16* __restrict__ WihT,
                                              __bf16* __restrict__ WhhT)
{
    __shared__ float tile[64][65];
    int gid = blockIdx.x;                         // 512 blocks
    int tid = threadIdx.x;
    const float* Wsrc = (gid >> 8) ? Whh : Wih;
    __bf16*      Wdst = (gid >> 8) ? WhhT : WihT;
    int rem = gid & 255;
    int k0 = (rem >> 5) << 6;
    int c0 = (rem & 31) << 6;
#pragma unroll
    for (int i = 0; i < 16; ++i) {
        int idx = tid + i * 256;
        int kl = idx >> 6, cl = idx & 63;
        tile[cl][kl] = Wsrc[(size_t)(k0 + kl) * 2048 + c0 + cl];
    }
    __syncthreads();
#pragma unroll
    for (int i = 0; i < 16; ++i) {
        int idx = tid + i * 256;
        int cl = idx >> 6, kl = idx & 63;
        Wdst[(size_t)(c0 + cl) * 512 + k0 + kl] = (__bf16)tile[cl][kl];
    }
}

// ------- W_rel fp32 [4][512][512] -> bf16 transposed [4][j][k] (post-LSTM) -------
__global__ __launch_bounds__(256) void k_cvtrel(const float* __restrict__ Wrel,
                                                __bf16* __restrict__ WrelT)
{
    __shared__ float tile[64][65];
    int rem = blockIdx.x;                         // 256 blocks: 4 rels x 8 k x 8 j
    int tid = threadIdx.x;
    int r = rem >> 6;
    int t6 = rem & 63;
    int k0 = (t6 >> 3) << 6, j0 = (t6 & 7) << 6;
    const float* src = Wrel + (size_t)r * 262144;
    __bf16*      dst = WrelT + (size_t)r * 262144;
#pragma unroll
    for (int i = 0; i < 16; ++i) {
        int idx = tid + i * 256;
        int kl = idx >> 6, jl = idx & 63;
        tile[jl][kl] = src[(size_t)(k0 + kl) * 512 + j0 + jl];
    }
    __syncthreads();
#pragma unroll
    for (int i = 0; i < 16; ++i) {
        int idx = tid + i * 256;
        int jl = idx >> 6, kl = idx & 63;
        dst[(size_t)(j0 + jl) * 512 + k0 + kl] = (__bf16)tile[jl][kl];
    }
}

// ---------------- embedding: X[t*256+n][k] = emb[word] + spk[spkid] (bf16) ----------------
__global__ __launch_bounds__(256) void k_embed(const int* __restrict__ src,
                                               const int* __restrict__ speaker,
                                               const float* __restrict__ emb,
                                               const float* __restrict__ spk,
                                               __bf16* __restrict__ X)
{
    int tid = blockIdx.x * 256 + threadIdx.x;   // 16384*64 threads
    int p  = tid >> 6;                          // t*256 + n
    int k8 = (tid & 63) << 3;
    int t = p >> 8, n = p & 255;
    int b = n >> 5, u = n & 31;
    int s = u * 64 + t;
    int word = src[s * 8 + b];                  // src (S,B,1)
    int sid  = speaker[b * 2048 + s];           // speaker (B,S)
    f32x4 e0 = *(const f32x4*)&emb[word * 512 + k8];
    f32x4 e1 = *(const f32x4*)&emb[word * 512 + k8 + 4];
    f32x4 s0 = *(const f32x4*)&spk[sid * 512 + k8];
    f32x4 s1 = *(const f32x4*)&spk[sid * 512 + k8 + 4];
    bf16x8 o;
#pragma unroll
    for (int j = 0; j < 4; ++j) {
        o[j]     = (__bf16)(e0[j] + s0[j]);
        o[4 + j] = (__bf16)(e1[j] + s1[j]);
    }
    *(bf16x8*)&X[p * 512 + k8] = o;
}

// ---------------- Xg = X @ W_ih + b (M=16384,K=512,N=2048), 128x128 tiles ----------------
__global__ __launch_bounds__(256) void k_gemm_xg(const __bf16* __restrict__ X,
                                                 const __bf16* __restrict__ Wt,
                                                 const float* __restrict__ bl,
                                                 __bf16* __restrict__ Xg)
{
    __shared__ __bf16 As[128 * 32];
    __shared__ __bf16 Bs[128 * 32];
    int tid = threadIdx.x;
    int w = tid >> 6, lane = tid & 63;
    int ml = lane & 15, q = lane >> 4;
    int m0 = blockIdx.y << 7, n0 = blockIdx.x << 7;
    f32x4 acc[4][4] = {};
    int mb = (w & 1) * 64, nb = (w >> 1) * 64;
    int lr = lane >> 2, lc = (lane & 3) << 3;
    for (int k0 = 0; k0 < 512; k0 += 32) {
#pragma unroll
        for (int i = 0; i < 2; ++i) {
            int r = w * 32 + i * 16;
            async_cp16(X  + (size_t)(m0 + r + lr) * 512 + k0 + lc, &As[r * 32]);
            async_cp16(Wt + (size_t)(n0 + r + lr) * 512 + k0 + lc, &Bs[r * 32]);
        }
        __syncthreads();
        bf16x8 af[4], bf_[4];
#pragma unroll
        for (int mi = 0; mi < 4; ++mi)
            af[mi] = *(const bf16x8*)&As[(mb + mi * 16 + ml) * 32 + q * 8];
#pragma unroll
        for (int ni = 0; ni < 4; ++ni)
            bf_[ni] = *(const bf16x8*)&Bs[(nb + ni * 16 + ml) * 32 + q * 8];
#pragma unroll
        for (int mi = 0; mi < 4; ++mi)
#pragma unroll
            for (int ni = 0; ni < 4; ++ni)
                acc[mi][ni] = __builtin_amdgcn_mfma_f32_16x16x32_bf16(af[mi], bf_[ni], acc[mi][ni], 0, 0, 0);
        __syncthreads();
    }
#pragma unroll
    for (int ni = 0; ni < 4; ++ni) {
        int col = n0 + nb + ni * 16 + ml;
        float bias = bl[col];
#pragma unroll
        for (int mi = 0; mi < 4; ++mi) {
#pragma unroll
            for (int r = 0; r < 4; ++r) {
                int row = m0 + mb + mi * 16 + q * 4 + r;
                Xg[(size_t)row * 2048 + col] = (__bf16)(acc[mi][ni][r] + bias);
            }
        }
    }
}

// ---------------- persistent LSTM, fence-free (all cross-block data via agent atomics) ----
// 256 blocks (1/CU). bx: j0=(bx&31)*16 h-cols (x4 gates), n0=(bx>>5)*32 rows.
// Waves: rh=w&1 row-half, kh=w>>1 K-half; LDS reduce across kh (kh==1 also adds Xg).
// h exchanged via relaxed AGENT-scope atomics (sc1 -> coherence point, bypasses stale L2,
// no cache wb/inv anywhere). Barrier: syncthreads (drains vmcnt) + relaxed atomic cnt/epoch.
__global__ __launch_bounds__(256, 1) void k_lstm_all(const __bf16* __restrict__ X,
                                                     const __bf16* __restrict__ WihT,
                                                     const __bf16* __restrict__ WhhT,
                                                     const float* __restrict__ bl,
                                                     const __bf16* __restrict__ Xg,
                                                     unsigned int* hbuf0,
                                                     unsigned int* hbuf1,
                                                     float* __restrict__ out,
                                                     int* bar, int fused)
{
    __shared__ float red[2][64][17];
    int tid = threadIdx.x;
    int w = tid >> 6, lane = tid & 63;
    int ml = lane & 15, q = lane >> 4;
    int rh = w & 1, kh = w >> 1;
    int bx = blockIdx.x;
    int j0 = (bx & 31) << 4;
    int n0 = (bx >> 5) << 5;
    int jc = j0 + ml;
    int rowA = n0 + rh * 16 + ml;
    int koff = kh * 256 + q * 8;

    // Preload W_hh^T fragments (t-invariant, 32 x bf16x8 = 128 VGPRs)
    bf16x8 Bh[32];
    {
        const __bf16* bh = WhhT + (size_t)jc * 512 + koff;
#pragma unroll
        for (int ki = 0; ki < 8; ++ki)
#pragma unroll
            for (int g = 0; g < 4; ++g)
                Bh[ki * 4 + g] = *(const bf16x8*)(bh + ((size_t)g << 18) + ki * 32);
    }
    float bias[4];
#pragma unroll
    for (int g = 0; g < 4; ++g) bias[g] = bl[g * 512 + jc];
    float c[4] = {0.f, 0.f, 0.f, 0.f};

    int* cnt   = bar;
    int* epoch = bar + 64;
    int base_u = (rowA * 512 + koff) >> 1;   // u32 index into h buffer

    for (int t = 0; t < 64; ++t) {
        unsigned int* hin_u  = (t & 1) ? hbuf1 : hbuf0;
        unsigned int* hout_u = (t & 1) ? hbuf0 : hbuf1;
        // A fragments of h(t): relaxed agent atomic u32 loads (bypass stale L2)
        bf16x8 av[8];
#pragma unroll
        for (int ki = 0; ki < 8; ++ki) {
            union { bf16x8 v; unsigned int u[4]; } tmp;
#pragma unroll
            for (int jj = 0; jj < 4; ++jj)
                tmp.u[jj] = __hip_atomic_load(hin_u + base_u + ki * 16 + jj,
                                              __ATOMIC_RELAXED, __HIP_MEMORY_SCOPE_AGENT);
            av[ki] = tmp.v;
        }
        f32x4 acc[4] = {};
#pragma unroll
        for (int ki = 0; ki < 8; ++ki)
#pragma unroll
            for (int g = 0; g < 4; ++g)
                acc[g] = __builtin_amdgcn_mfma_f32_16x16x32_bf16(av[ki], Bh[ki * 4 + g], acc[g], 0, 0, 0);
        if (fused) {       // fallback: stream W_ih^T + X per step
            const __bf16* xrow = X + (((size_t)(t << 8) + rowA) << 9) + koff;
            const __bf16* bi = WihT + (size_t)jc * 512 + koff;
#pragma unroll
            for (int ki = 0; ki < 8; ++ki) {
                bf16x8 xv = *(const bf16x8*)(xrow + ki * 32);
#pragma unroll
                for (int g = 0; g < 4; ++g)
                    acc[g] = __builtin_amdgcn_mfma_f32_16x16x32_bf16(
                        xv, *(const bf16x8*)(bi + ((size_t)g << 18) + ki * 32), acc[g], 0, 0, 0);
            }
        }
        if (kh == 1) {
            if (!fused) {  // fold Xg(t) into the K-half-1 partial
#pragma unroll
                for (int r = 0; r < 4; ++r) {
                    int n = n0 + rh * 16 + q * 4 + r;
                    const __bf16* xg = Xg + ((size_t)t * 256 + n) * 2048;
#pragma unroll
                    for (int g = 0; g < 4; ++g)
                        acc[g][r] += (float)xg[g * 512 + jc];
                }
            }
#pragma unroll
            for (int g = 0; g < 4; ++g)
#pragma unroll
                for (int r = 0; r < 4; ++r)
                    red[rh][lane][g * 4 + r] = acc[g][r];
        }
        __syncthreads();
        if (kh == 0) {
#pragma unroll
            for (int r = 0; r < 4; ++r) {
                int n = n0 + rh * 16 + q * 4 + r;
                float pi = acc[0][r] + red[rh][lane][0 * 4 + r];
                float pf = acc[1][r] + red[rh][lane][1 * 4 + r];
                float pg = acc[2][r] + red[rh][lane][2 * 4 + r];
                float po = acc[3][r] + red[rh][lane][3 * 4 + r];
                if (fused) { pi += bias[0]; pf += bias[1]; pg += bias[2]; po += bias[3]; }
                float ig = sigm(pi), fg = sigm(pf);
                float gg = tanhf(pg), og = sigm(po);
                float cn = fg * c[r] + ig * gg;
                c[r] = cn;
                float hn = og * tanhf(cn);
                union { __bf16 b; unsigned short s; } hb; hb.b = (__bf16)hn;
                __hip_atomic_store((unsigned short*)hout_u + n * 512 + jc, hb.s,
                                   __ATOMIC_RELAXED, __HIP_MEMORY_SCOPE_AGENT);
                int b = n >> 5, u = n & 31;
                int s = u * 64 + t;
                out[OFF_MB + ((size_t)s * 8 + b) * 512 + jc] = hn;
            }
        }
        if (t < 63) {
            __syncthreads();   // drains vmcnt: h stores are at the coherence point
            if (tid == 0) {
                int prev = __hip_atomic_fetch_add(cnt, 1, __ATOMIC_RELAXED, __HIP_MEMORY_SCOPE_AGENT);
                if (prev == 256 * (t + 1) - 1) {
                    __hip_atomic_store(epoch, t + 1, __ATOMIC_RELAXED, __HIP_MEMORY_SCOPE_AGENT);
                } else {
                    while (__hip_atomic_load(epoch, __ATOMIC_RELAXED, __HIP_MEMORY_SCOPE_AGENT) < t + 1)
                        __builtin_amdgcn_s_sleep(1);
                }
            }
            __syncthreads();
        }
    }
}

// ---------------- nodes: utt_h + global mean node; also zero agg ----------------
__global__ __launch_bounds__(256) void k_nodes(const __bf16* __restrict__ hT,
                                               float* __restrict__ nodes,
                                               __bf16* __restrict__ nodesB,
                                               float* __restrict__ agg)
{
    int b = blockIdx.x;
    int tid = threadIdx.x;
    for (int i = b * 256 + tid; i < 135168; i += 2048) agg[i] = 0.f;
    for (int k = tid; k < 512; k += 256) {
        float sum = 0.f;
        for (int u = 0; u < 32; ++u) {
            float v = (float)hT[(b * 32 + u) * 512 + k];
            nodes[(b * 33 + u) * 512 + k] = v;
            nodesB[(b * 33 + u) * 512 + k] = (__bf16)v;
            sum += v;
        }
        float gm = sum * (1.0f / 32.0f);
        nodes[(b * 33 + 32) * 512 + k] = gm;
        nodesB[(b * 33 + 32) * 512 + k] = (__bf16)gm;
    }
}

// ---------------- edges as one MFMA GEMM, rel-masked atomic scatter ----------------
__global__ __launch_bounds__(256) void k_edges_mm(const __bf16* __restrict__ nodesB,
                                                  const __bf16* __restrict__ WrelT,
                                                  const int* __restrict__ edge_src,
                                                  const int* __restrict__ edge_dst,
                                                  const int* __restrict__ rels,
                                                  float* __restrict__ agg)
{
    __shared__ __bf16 As[128 * 32];
    __shared__ __bf16 Bs[128 * 32];
    int tid = threadIdx.x;
    int w = tid >> 6, lane = tid & 63;
    int ml = lane & 15, q = lane >> 4;
    int by = blockIdx.y;
    int n0 = blockIdx.x << 7;
    int rel = n0 >> 9, jbase = n0 & 511;
    int mb = (w & 1) * 64, nb = (w >> 1) * 64;
    int lr = lane >> 2, lc = (lane & 3) << 3;
    const __bf16* ap[2]; const __bf16* bp[2];
#pragma unroll
    for (int i = 0; i < 2; ++i) {
        int r = w * 32 + i * 16 + lr;
        int es = edge_src[by * 128 + r];
        ap[i] = nodesB + ((size_t)by * 33 + es) * 512 + lc;
        bp[i] = WrelT + (size_t)rel * 262144 + (size_t)(jbase + r) * 512 + lc;
    }
    f32x4 acc[4][4] = {};
    for (int k0 = 0; k0 < 512; k0 += 32) {
#pragma unroll
        for (int i = 0; i < 2; ++i) {
            int r = w * 32 + i * 16;
            async_cp16(ap[i] + k0, &As[r * 32]);
            async_cp16(bp[i] + k0, &Bs[r * 32]);
        }
        __syncthreads();
        bf16x8 af[4], bf_[4];
#pragma unroll
        for (int mi = 0; mi < 4; ++mi)
            af[mi] = *(const bf16x8*)&As[(mb + mi * 16 + ml) * 32 + q * 8];
#pragma unroll
        for (int ni = 0; ni < 4; ++ni)
            bf_[ni] = *(const bf16x8*)&Bs[(nb + ni * 16 + ml) * 32 + q * 8];
#pragma unroll
        for (int mi = 0; mi < 4; ++mi)
#pragma unroll
            for (int ni = 0; ni < 4; ++ni)
                acc[mi][ni] = __builtin_amdgcn_mfma_f32_16x16x32_bf16(af[mi], bf_[ni], acc[mi][ni], 0, 0, 0);
        __syncthreads();
    }
#pragma unroll
    for (int mi = 0; mi < 4; ++mi) {
#pragma unroll
        for (int r = 0; r < 4; ++r) {
            int m = mb + mi * 16 + q * 4 + r;
            int eidx = by * 128 + m;
            int er = rels[eidx];
            if (er != rel) continue;
            int ed = edge_dst[eidx];
            float* dst = &agg[((size_t)by * 33 + ed) * 512 + jbase];
#pragma unroll
            for (int ni = 0; ni < 4; ++ni)
                atomicAdd(dst + nb + ni * 16 + ml, acc[mi][ni][r]);
        }
    }
}

// ---------------- GNN gate fusion: grid (264 nodes, 8 j-tiles), in-block K-split ----------------
__global__ __launch_bounds__(256) void k_gnn(const float* __restrict__ nodes,
                                             const float* __restrict__ agg,
                                             const float* __restrict__ Wself,
                                             const float* __restrict__ bgnn,
                                             const float* __restrict__ Wg1,
                                             const float* __restrict__ Wg2,
                                             float* __restrict__ newn,
                                             float* __restrict__ out)
{
    __shared__ float nd[512], ag[512];
    __shared__ float red[4][3][64];
    int vg = blockIdx.x;
    int j0 = blockIdx.y << 6;
    int b = vg / 33, v = vg % 33;
    int tid = threadIdx.x;
    for (int k = tid; k < 512; k += 256) {
        nd[k] = nodes[vg * 512 + k];
        ag[k] = agg[vg * 512 + k];
    }
    __syncthreads();
    int jl = tid & 63, kq = tid >> 6;
    int jj = j0 + jl;
    int kbase = kq << 7;
    float a_s = 0.f, a1 = 0.f, a2 = 0.f;
#pragma unroll 4
    for (int kk = 0; kk < 128; ++kk) {
        int k = kbase + kk;
        float ndk = nd[k], agk = ag[k];
        a_s += ndk * Wself[k * 512 + jj];
        a1  += ndk * Wg1[k * 512 + jj];
        a2  += agk * Wg2[k * 512 + jj];
    }
    red[kq][0][jl] = a_s;
    red[kq][1][jl] = a1;
    red[kq][2][jl] = a2;
    __syncthreads();
    if (tid < 64) {
        int j = j0 + tid;
        float s0 = red[0][0][tid] + red[1][0][tid] + red[2][0][tid] + red[3][0][tid];
        float s1 = red[0][1][tid] + red[1][1][tid] + red[2][1][tid] + red[3][1][tid];
        float s2 = red[0][2][tid] + red[1][2][tid] + red[2][2][tid] + red[3][2][tid];
        float outv = fmaxf(s0 + ag[j] + bgnn[j], 0.f);
        float gate = sigm(s1 + s2);
        float newv = gate * outv + (1.f - gate) * nd[j];
        newn[vg * 512 + j] = newv;
        if (v == 32) {
            out[OFF_ENCH + b * 512 + j] = newv;
            out[OFF_ENCC + b * 512 + j] = newv;
        }
    }
}

// ---------------- mbu: broadcast utt_upd over L into (S,B,H) ----------------
__global__ __launch_bounds__(256) void k_mbu(const float* __restrict__ newn,
                                             float* __restrict__ out)
{
    int idx = blockIdx.x * 256 + threadIdx.x;
    int k8 = (idx & 63) << 3;
    int rest = idx >> 6;
    int b = rest & 7;
    int s = rest >> 3;
    int u = s >> 6;
    const float* sp = &newn[(b * 33 + u) * 512 + k8];
    f32x4 v0 = *(const f32x4*)sp;
    f32x4 v1 = *(const f32x4*)(sp + 4);
    float* dp = &out[OFF_MBU + (s * 8 + b) * 512 + k8];
    *(f32x4*)dp = v0;
    *(f32x4*)(dp + 4) = v1;
}

extern "C" void kernel_launch(void* const* d_in, const int* in_sizes, int n_in,
                              void* d_out, int out_size, void* d_ws, size_t ws_size,
                              hipStream_t stream)
{
    (void)in_sizes; (void)n_in; (void)out_size;
    const int*   src      = (const int*)d_in[0];
    const int*   speaker  = (const int*)d_in[2];
    const int*   lengths  = (const int*)d_in[3];
    const int*   edge_src = (const int*)d_in[4];
    const int*   edge_dst = (const int*)d_in[5];
    const int*   rels     = (const int*)d_in[6];
    const float* emb   = (const float*)d_in[7];
    const float* spk   = (const float*)d_in[8];
    const float* Wih   = (const float*)d_in[9];
    const float* Whh   = (const float*)d_in[10];
    const float* bl    = (const float*)d_in[11];
    const float* Wrel  = (const float*)d_in[12];
    const float* Wself = (const float*)d_in[13];
    const float* bgnn  = (const float*)d_in[14];
    const float* Wg1   = (const float*)d_in[15];
    const float* Wg2   = (const float*)d_in[16];
    float* out = (float*)d_out;
    char*  ws  = (char*)d_ws;

    __bf16* X      = (__bf16*)(ws + WS_X);
    __bf16* WrelT  = (__bf16*)(ws + WS_WRELT);
    float*  agg    = (float*)(ws + WS_AGG);
    float*  nodes  = (float*)(ws + WS_NODES);
    __bf16* nodesB = (__bf16*)(ws + WS_NODESB);
    float*  newn   = (float*)(ws + WS_NEWN);
    __bf16* WihT   = (__bf16*)(ws + WS_WIH);
    __bf16* WhhT   = (__bf16*)(ws + WS_WHH);
    unsigned int* hb0 = (unsigned int*)(ws + WS_HBUF);
    unsigned int* hb1 = hb0 + 65536;
    int*    bar    = (int*)(ws + WS_BAR);
    __bf16* Xg     = (__bf16*)(ws + WS_XG);

    int split = (ws_size >= WS_SPLIT_NEED) ? 1 : 0;

    k_init<<<581, 256, 0, stream>>>((unsigned int*)(ws + WS_HBUF), lengths, out);
    k_embed<<<4096, 256, 0, stream>>>(src, speaker, emb, spk, X);
    k_cvtw<<<512, 256, 0, stream>>>(Wih, Whh, WihT, WhhT);
    if (split)
        k_gemm_xg<<<dim3(16, 128), 256, 0, stream>>>(X, WihT, bl, Xg);
    k_lstm_all<<<256, 256, 0, stream>>>(X, WihT, WhhT, bl, Xg, hb0, hb1, out, bar,
                                        split ? 0 : 1);
    k_cvtrel<<<256, 256, 0, stream>>>(Wrel, WrelT);
    k_nodes<<<8, 256, 0, stream>>>((const __bf16*)hb0, nodes, nodesB, agg);
    k_edges_mm<<<dim3(16, 8), 256, 0, stream>>>(nodesB, WrelT, edge_src, edge_dst, rels, agg);
    k_gnn<<<dim3(264, 8), 256, 0, stream>>>(nodes, agg, Wself, bgnn, Wg1, Wg2, newn, out);
    k_mbu<<<4096, 256, 0, stream>>>(newn, out);
}